// Round 8
// baseline (404.306 us; speedup 1.0000x reference)
//
#include <hip/hip_runtime.h>
#include <hip/hip_fp16.h>

#define DD 4096
#define NROWS 16384
#define EPS 1e-6f

typedef float  fx4 __attribute__((ext_vector_type(4)));
typedef int    ix4 __attribute__((ext_vector_type(4)));

// ws layout:
//   +0          : float gmax
//   +256        : float rowmax[16384]        (A, consumed)
//   +256+64K    : float rstd[16384]          (A, consumed)
//   +256+128K   : float rowmax_b[16384]      (ablation B, unused downstream)
//   +256+192K   : float rstd_b[16384]
//   +256+256K   : float rowmax_c[16384]      (ablation C, unused downstream)
//   +256+320K   : float rstd_c[16384]
//   +1MB        : fp16 yg [64M]  (128 MB, A, consumed by pass2)
//   +160MB      : fp16 yg2[64M]  (128 MB, C, unused downstream)

struct H4 { __half2 a, b; };  // 4 halfs, 8 bytes

// ===== A: production pass1 — EXACT round-4 structure (best total 203.1) =====
__global__ __launch_bounds__(256) void pass1(
    const float* __restrict__ x, const float* __restrict__ res,
    const float* __restrict__ gamma, H4* __restrict__ yg,
    float* __restrict__ rstd, float* __restrict__ rowmax) {
  const int row = blockIdx.x;
  const int t = threadIdx.x;
  const fx4* x4 = (const fx4*)(x + (size_t)row * DD);
  const fx4* r4 = (const fx4*)(res + (size_t)row * DD);
  const fx4* g4 = (const fx4*)gamma;
  H4* yrow = yg + (size_t)row * (DD / 4);

  float ss = 0.f, mx = 0.f;
#pragma unroll
  for (int i = 0; i < 4; ++i) {
    const int idx = t + i * 256;
    fx4 xv = x4[idx], rv = r4[idx], gv = g4[idx];
    float y0 = xv.x + rv.x, y1 = xv.y + rv.y;
    float y2 = xv.z + rv.z, y3 = xv.w + rv.w;
    ss += y0 * y0 + y1 * y1 + y2 * y2 + y3 * y3;
    float p0 = y0 * gv.x, p1 = y1 * gv.y, p2 = y2 * gv.z, p3 = y3 * gv.w;
    mx = fmaxf(mx, fmaxf(fmaxf(fabsf(p0), fabsf(p1)),
                         fmaxf(fabsf(p2), fabsf(p3))));
    H4 h;
    h.a = __floats2half2_rn(p0, p1);
    h.b = __floats2half2_rn(p2, p3);
    yrow[idx] = h;
  }
#pragma unroll
  for (int off = 32; off > 0; off >>= 1) {
    ss += __shfl_down(ss, off, 64);
    mx = fmaxf(mx, __shfl_down(mx, off, 64));
  }
  __shared__ float s_ss[4], s_mx[4];
  const int wave = t >> 6, lane = t & 63;
  if (lane == 0) { s_ss[wave] = ss; s_mx[wave] = mx; }
  __syncthreads();
  if (t == 0) {
    float tss = s_ss[0] + s_ss[1] + s_ss[2] + s_ss[3];
    float tmx = fmaxf(fmaxf(s_mx[0], s_mx[1]), fmaxf(s_mx[2], s_mx[3]));
    float rs = rsqrtf(tss * (1.0f / DD) + EPS);
    rstd[row] = rs;
    rowmax[row] = tmx * rs;
  }
}

// ===== B: ablation — identical loads+reduction, NO yg store =====
__global__ __launch_bounds__(256) void pass1_nostore(
    const float* __restrict__ x, const float* __restrict__ res,
    const float* __restrict__ gamma,
    float* __restrict__ rstd_b, float* __restrict__ rowmax_b) {
  const int row = blockIdx.x;
  const int t = threadIdx.x;
  const fx4* x4 = (const fx4*)(x + (size_t)row * DD);
  const fx4* r4 = (const fx4*)(res + (size_t)row * DD);
  const fx4* g4 = (const fx4*)gamma;
  float ss = 0.f, mx = 0.f;
#pragma unroll
  for (int i = 0; i < 4; ++i) {
    const int idx = t + i * 256;
    fx4 xv = x4[idx], rv = r4[idx], gv = g4[idx];
    float y0 = xv.x + rv.x, y1 = xv.y + rv.y;
    float y2 = xv.z + rv.z, y3 = xv.w + rv.w;
    ss += y0 * y0 + y1 * y1 + y2 * y2 + y3 * y3;
    mx = fmaxf(mx, fmaxf(fmaxf(fabsf(y0 * gv.x), fabsf(y1 * gv.y)),
                         fmaxf(fabsf(y2 * gv.z), fabsf(y3 * gv.w))));
  }
#pragma unroll
  for (int off = 32; off > 0; off >>= 1) {
    ss += __shfl_down(ss, off, 64);
    mx = fmaxf(mx, __shfl_down(mx, off, 64));
  }
  __shared__ float s_ss[4], s_mx[4];
  const int wave = t >> 6, lane = t & 63;
  if (lane == 0) { s_ss[wave] = ss; s_mx[wave] = mx; }
  __syncthreads();
  if (t == 0) {
    float tss = s_ss[0] + s_ss[1] + s_ss[2] + s_ss[3];
    float tmx = fmaxf(fmaxf(s_mx[0], s_mx[1]), fmaxf(s_mx[2], s_mx[3]));
    float rs = rsqrtf(tss * (1.0f / DD) + EPS);
    rstd_b[row] = rs;
    rowmax_b[row] = tmx * rs;
  }
}

// ===== C: ablation — identical to A but NON-TEMPORAL yg stores =====
__global__ __launch_bounds__(256) void pass1_ntstore(
    const float* __restrict__ x, const float* __restrict__ res,
    const float* __restrict__ gamma, __half* __restrict__ yg2,
    float* __restrict__ rstd_c, float* __restrict__ rowmax_c) {
  const int row = blockIdx.x;
  const int t = threadIdx.x;
  const fx4* x4 = (const fx4*)(x + (size_t)row * DD);
  const fx4* r4 = (const fx4*)(res + (size_t)row * DD);
  const fx4* g4 = (const fx4*)gamma;
  // 8B NT stores: 2 halfs packed in uint, stored as uint2? Use ulong per slot.
  unsigned long long* yrow = (unsigned long long*)(yg2 + (size_t)row * DD);

  float ss = 0.f, mx = 0.f;
#pragma unroll
  for (int i = 0; i < 4; ++i) {
    const int idx = t + i * 256;
    fx4 xv = x4[idx], rv = r4[idx], gv = g4[idx];
    float y0 = xv.x + rv.x, y1 = xv.y + rv.y;
    float y2 = xv.z + rv.z, y3 = xv.w + rv.w;
    ss += y0 * y0 + y1 * y1 + y2 * y2 + y3 * y3;
    float p0 = y0 * gv.x, p1 = y1 * gv.y, p2 = y2 * gv.z, p3 = y3 * gv.w;
    mx = fmaxf(mx, fmaxf(fmaxf(fabsf(p0), fabsf(p1)),
                         fmaxf(fabsf(p2), fabsf(p3))));
    union { unsigned long long u; __half2 h2[2]; } pk;
    pk.h2[0] = __floats2half2_rn(p0, p1);
    pk.h2[1] = __floats2half2_rn(p2, p3);
    __builtin_nontemporal_store(pk.u, &yrow[idx]);
  }
#pragma unroll
  for (int off = 32; off > 0; off >>= 1) {
    ss += __shfl_down(ss, off, 64);
    mx = fmaxf(mx, __shfl_down(mx, off, 64));
  }
  __shared__ float s_ss[4], s_mx[4];
  const int wave = t >> 6, lane = t & 63;
  if (lane == 0) { s_ss[wave] = ss; s_mx[wave] = mx; }
  __syncthreads();
  if (t == 0) {
    float tss = s_ss[0] + s_ss[1] + s_ss[2] + s_ss[3];
    float tmx = fmaxf(fmaxf(s_mx[0], s_mx[1]), fmaxf(s_mx[2], s_mx[3]));
    float rs = rsqrtf(tss * (1.0f / DD) + EPS);
    rstd_c[row] = rs;
    rowmax_c[row] = tmx * rs;
  }
}

__global__ __launch_bounds__(1024) void reduce_gmax(
    const float* __restrict__ rowmax, float* __restrict__ gmax) {
  const int t = threadIdx.x;
  float m = 0.f;
#pragma unroll
  for (int i = 0; i < NROWS / 1024; ++i) m = fmaxf(m, rowmax[t + i * 1024]);
#pragma unroll
  for (int off = 32; off > 0; off >>= 1) m = fmaxf(m, __shfl_down(m, off, 64));
  __shared__ float s[16];
  if ((t & 63) == 0) s[t >> 6] = m;
  __syncthreads();
  if (t == 0) {
    float r = s[0];
#pragma unroll
    for (int i = 1; i < 16; ++i) r = fmaxf(r, s[i]);
    *gmax = r;
  }
}

// Production pass2 — exact round-4 structure (plain stores).
__global__ __launch_bounds__(256) void pass2(
    const __half* __restrict__ yg, const float* __restrict__ rstd,
    const float* __restrict__ gmax, int* __restrict__ out) {
  const int row = blockIdx.x >> 1;
  const float c = rstd[row] * (127.0f / *gmax);
  const size_t base = ((size_t)blockIdx.x * 256 + threadIdx.x) * 8;
  union { ix4 v; __half h[8]; } u;
  u.v = *(const ix4*)(yg + base);
  ix4 q0, q1;
  q0.x = min(max(__float2int_rn(__half2float(u.h[0]) * c), -128), 127);
  q0.y = min(max(__float2int_rn(__half2float(u.h[1]) * c), -128), 127);
  q0.z = min(max(__float2int_rn(__half2float(u.h[2]) * c), -128), 127);
  q0.w = min(max(__float2int_rn(__half2float(u.h[3]) * c), -128), 127);
  q1.x = min(max(__float2int_rn(__half2float(u.h[4]) * c), -128), 127);
  q1.y = min(max(__float2int_rn(__half2float(u.h[5]) * c), -128), 127);
  q1.z = min(max(__float2int_rn(__half2float(u.h[6]) * c), -128), 127);
  q1.w = min(max(__float2int_rn(__half2float(u.h[7]) * c), -128), 127);
  *(ix4*)(out + base) = q0;
  *(ix4*)(out + base + 4) = q1;
}

// ---- Fallback (ws too small) ----
__global__ __launch_bounds__(256) void pass2_nb(
    const float* __restrict__ x, const float* __restrict__ res,
    const float* __restrict__ gamma, const float* __restrict__ rstd,
    const float* __restrict__ gmax, int* __restrict__ out) {
  const int row = blockIdx.x;
  const int t = threadIdx.x;
  const float c = rstd[row] * (127.0f / *gmax);
  const fx4* x4 = (const fx4*)(x + (size_t)row * DD);
  const fx4* r4 = (const fx4*)(res + (size_t)row * DD);
  const fx4* g4 = (const fx4*)gamma;
  ix4* o4 = (ix4*)(out + (size_t)row * DD);
#pragma unroll
  for (int i = 0; i < 4; ++i) {
    const int idx = t + i * 256;
    fx4 xv = x4[idx], rv = r4[idx], gv = g4[idx];
    ix4 q;
    q.x = min(max(__float2int_rn((xv.x + rv.x) * gv.x * c), -128), 127);
    q.y = min(max(__float2int_rn((xv.y + rv.y) * gv.y * c), -128), 127);
    q.z = min(max(__float2int_rn((xv.z + rv.z) * gv.z * c), -128), 127);
    q.w = min(max(__float2int_rn((xv.w + rv.w) * gv.w * c), -128), 127);
    o4[idx] = q;
  }
}

extern "C" void kernel_launch(void* const* d_in, const int* in_sizes, int n_in,
                              void* d_out, int out_size, void* d_ws, size_t ws_size,
                              hipStream_t stream) {
  const float* x     = (const float*)d_in[0];
  const float* res   = (const float*)d_in[1];
  const float* gamma = (const float*)d_in[2];
  int* out = (int*)d_out;

  char* ws = (char*)d_ws;
  float* gmax     = (float*)ws;
  float* rowmax   = (float*)(ws + 256);
  float* rstd     = (float*)(ws + 256 + 64 * 1024);
  float* rowmax_b = (float*)(ws + 256 + 128 * 1024);
  float* rstd_b   = (float*)(ws + 256 + 192 * 1024);
  float* rowmax_c = (float*)(ws + 256 + 256 * 1024);
  float* rstd_c   = (float*)(ws + 256 + 320 * 1024);
  const size_t yg_off  = (size_t)1 << 20;          // 1 MB
  const size_t yg2_off = (size_t)160 << 20;        // 160 MB
  const size_t need = yg2_off + (size_t)NROWS * DD * 2;  // ~288 MB

  if (ws_size >= need) {
    H4*     yg  = (H4*)(ws + yg_off);
    __half* yg2 = (__half*)(ws + yg2_off);
    // Ablation arms first (outputs unused downstream; full-size so they
    // appear as distinct profiled dispatches in the same BW regime).
    pass1_nostore<<<NROWS, 256, 0, stream>>>(x, res, gamma, rstd_b, rowmax_b);
    pass1_ntstore<<<NROWS, 256, 0, stream>>>(x, res, gamma, yg2, rstd_c, rowmax_c);
    // Production pipeline (A last so its yg is freshest in L3 for pass2).
    pass1<<<NROWS, 256, 0, stream>>>(x, res, gamma, yg, rstd, rowmax);
    reduce_gmax<<<1, 1024, 0, stream>>>(rowmax, gmax);
    pass2<<<((size_t)NROWS * DD) / 2048, 256, 0, stream>>>(
        (const __half*)yg, rstd, gmax, out);
  } else {
    pass1_nostore<<<NROWS, 256, 0, stream>>>(x, res, gamma, rstd, rowmax);
    reduce_gmax<<<1, 1024, 0, stream>>>(rowmax, gmax);
    pass2_nb<<<NROWS, 256, 0, stream>>>(x, res, gamma, rstd, gmax, out);
  }
}

// Round 9
// 206.637 us; speedup vs baseline: 1.9566x; 1.9566x over previous
//
#include <hip/hip_runtime.h>
#include <hip/hip_fp16.h>

#define DD 4096
#define NROWS 16384
#define EPS 1e-6f

typedef float  fx4 __attribute__((ext_vector_type(4)));
typedef int    ix4 __attribute__((ext_vector_type(4)));

// ws layout:
//   +0        : float gmax
//   +256      : float rowmax[16384]
//   +256+64K  : float rstd[16384]
//   +1MB      : fp16 yg[64M] = (x+res)*gamma, UNNORMALIZED (128 MB)

// Pass 1: block-per-row (r4 structure), yg written with NON-TEMPORAL stores.
// Ablation (r8): plain stores poison the read pipeline via L2 write-allocate
// (163 us); no-store runs ~85 us; NT stores ~116 us.
__global__ __launch_bounds__(256) void pass1(
    const float* __restrict__ x, const float* __restrict__ res,
    const float* __restrict__ gamma, __half* __restrict__ yg,
    float* __restrict__ rstd, float* __restrict__ rowmax) {
  const int row = blockIdx.x;
  const int t = threadIdx.x;
  const fx4* x4 = (const fx4*)(x + (size_t)row * DD);
  const fx4* r4 = (const fx4*)(res + (size_t)row * DD);
  const fx4* g4 = (const fx4*)gamma;
  unsigned long long* yrow = (unsigned long long*)(yg + (size_t)row * DD);

  float ss = 0.f, mx = 0.f;
#pragma unroll
  for (int i = 0; i < 4; ++i) {
    const int idx = t + i * 256;  // coalesced: wave reads 1KB/stream/instr
    fx4 xv = x4[idx], rv = r4[idx], gv = g4[idx];
    float y0 = xv.x + rv.x, y1 = xv.y + rv.y;
    float y2 = xv.z + rv.z, y3 = xv.w + rv.w;
    ss += y0 * y0 + y1 * y1 + y2 * y2 + y3 * y3;
    float p0 = y0 * gv.x, p1 = y1 * gv.y, p2 = y2 * gv.z, p3 = y3 * gv.w;
    mx = fmaxf(mx, fmaxf(fmaxf(fabsf(p0), fabsf(p1)),
                         fmaxf(fabsf(p2), fabsf(p3))));
    union { unsigned long long u; __half2 h2[2]; } pk;
    pk.h2[0] = __floats2half2_rn(p0, p1);
    pk.h2[1] = __floats2half2_rn(p2, p3);
    __builtin_nontemporal_store(pk.u, &yrow[idx]);  // bypass L2 write-alloc
  }

#pragma unroll
  for (int off = 32; off > 0; off >>= 1) {
    ss += __shfl_down(ss, off, 64);
    mx = fmaxf(mx, __shfl_down(mx, off, 64));
  }
  __shared__ float s_ss[4], s_mx[4];
  const int wave = t >> 6, lane = t & 63;
  if (lane == 0) { s_ss[wave] = ss; s_mx[wave] = mx; }
  __syncthreads();
  if (t == 0) {
    float tss = s_ss[0] + s_ss[1] + s_ss[2] + s_ss[3];
    float tmx = fmaxf(fmaxf(s_mx[0], s_mx[1]), fmaxf(s_mx[2], s_mx[3]));
    float rs = rsqrtf(tss * (1.0f / DD) + EPS);
    rstd[row] = rs;
    rowmax[row] = tmx * rs;  // |normalized output| row max
  }
}

__global__ __launch_bounds__(1024) void reduce_gmax(
    const float* __restrict__ rowmax, float* __restrict__ gmax) {
  const int t = threadIdx.x;
  float m = 0.f;
#pragma unroll
  for (int i = 0; i < NROWS / 1024; ++i) m = fmaxf(m, rowmax[t + i * 1024]);
#pragma unroll
  for (int off = 32; off > 0; off >>= 1) m = fmaxf(m, __shfl_down(m, off, 64));
  __shared__ float s[16];
  if ((t & 63) == 0) s[t >> 6] = m;
  __syncthreads();
  if (t == 0) {
    float r = s[0];
#pragma unroll
    for (int i = 1; i < 16; ++i) r = fmaxf(r, s[i]);
    *gmax = r;
  }
}

// Pass 2: q = clamp(rn(fp16(y*gamma) * rstd[row] * 127/gmax)). Block covers
// 2048 contiguous elements = half a row -> uniform rstd. Plain stores
// (NT out-stores measured +10us in r6).
__global__ __launch_bounds__(256) void pass2(
    const __half* __restrict__ yg, const float* __restrict__ rstd,
    const float* __restrict__ gmax, int* __restrict__ out) {
  const int row = blockIdx.x >> 1;
  const float c = rstd[row] * (127.0f / *gmax);
  const size_t base = ((size_t)blockIdx.x * 256 + threadIdx.x) * 8;
  union { ix4 v; __half h[8]; } u;
  u.v = *(const ix4*)(yg + base);  // 16B coalesced fp16 load
  ix4 q0, q1;
  q0.x = min(max(__float2int_rn(__half2float(u.h[0]) * c), -128), 127);
  q0.y = min(max(__float2int_rn(__half2float(u.h[1]) * c), -128), 127);
  q0.z = min(max(__float2int_rn(__half2float(u.h[2]) * c), -128), 127);
  q0.w = min(max(__float2int_rn(__half2float(u.h[3]) * c), -128), 127);
  q1.x = min(max(__float2int_rn(__half2float(u.h[4]) * c), -128), 127);
  q1.y = min(max(__float2int_rn(__half2float(u.h[5]) * c), -128), 127);
  q1.z = min(max(__float2int_rn(__half2float(u.h[6]) * c), -128), 127);
  q1.w = min(max(__float2int_rn(__half2float(u.h[7]) * c), -128), 127);
  *(ix4*)(out + base) = q0;
  *(ix4*)(out + base + 4) = q1;
}

// ---- Fallback (ws too small): recompute path, atomic-free ----
__global__ __launch_bounds__(256) void pass1_nb(
    const float* __restrict__ x, const float* __restrict__ res,
    const float* __restrict__ gamma, float* __restrict__ rstd,
    float* __restrict__ rowmax) {
  const int row = blockIdx.x;
  const int t = threadIdx.x;
  const fx4* x4 = (const fx4*)(x + (size_t)row * DD);
  const fx4* r4 = (const fx4*)(res + (size_t)row * DD);
  const fx4* g4 = (const fx4*)gamma;
  float ss = 0.f, mx = 0.f;
#pragma unroll
  for (int i = 0; i < 4; ++i) {
    const int idx = t + i * 256;
    fx4 xv = x4[idx], rv = r4[idx], gv = g4[idx];
    float y0 = xv.x + rv.x, y1 = xv.y + rv.y;
    float y2 = xv.z + rv.z, y3 = xv.w + rv.w;
    ss += y0 * y0 + y1 * y1 + y2 * y2 + y3 * y3;
    mx = fmaxf(mx, fmaxf(fmaxf(fabsf(y0 * gv.x), fabsf(y1 * gv.y)),
                         fmaxf(fabsf(y2 * gv.z), fabsf(y3 * gv.w))));
  }
#pragma unroll
  for (int off = 32; off > 0; off >>= 1) {
    ss += __shfl_down(ss, off, 64);
    mx = fmaxf(mx, __shfl_down(mx, off, 64));
  }
  __shared__ float s_ss[4], s_mx[4];
  const int wave = t >> 6, lane = t & 63;
  if (lane == 0) { s_ss[wave] = ss; s_mx[wave] = mx; }
  __syncthreads();
  if (t == 0) {
    float tss = s_ss[0] + s_ss[1] + s_ss[2] + s_ss[3];
    float tmx = fmaxf(fmaxf(s_mx[0], s_mx[1]), fmaxf(s_mx[2], s_mx[3]));
    float rs = rsqrtf(tss * (1.0f / DD) + EPS);
    rstd[row] = rs;
    rowmax[row] = tmx * rs;
  }
}

__global__ __launch_bounds__(256) void pass2_nb(
    const float* __restrict__ x, const float* __restrict__ res,
    const float* __restrict__ gamma, const float* __restrict__ rstd,
    const float* __restrict__ gmax, int* __restrict__ out) {
  const int row = blockIdx.x;
  const int t = threadIdx.x;
  const float c = rstd[row] * (127.0f / *gmax);
  const fx4* x4 = (const fx4*)(x + (size_t)row * DD);
  const fx4* r4 = (const fx4*)(res + (size_t)row * DD);
  const fx4* g4 = (const fx4*)gamma;
  ix4* o4 = (ix4*)(out + (size_t)row * DD);
#pragma unroll
  for (int i = 0; i < 4; ++i) {
    const int idx = t + i * 256;
    fx4 xv = x4[idx], rv = r4[idx], gv = g4[idx];
    ix4 q;
    q.x = min(max(__float2int_rn((xv.x + rv.x) * gv.x * c), -128), 127);
    q.y = min(max(__float2int_rn((xv.y + rv.y) * gv.y * c), -128), 127);
    q.z = min(max(__float2int_rn((xv.z + rv.z) * gv.z * c), -128), 127);
    q.w = min(max(__float2int_rn((xv.w + rv.w) * gv.w * c), -128), 127);
    o4[idx] = q;
  }
}

extern "C" void kernel_launch(void* const* d_in, const int* in_sizes, int n_in,
                              void* d_out, int out_size, void* d_ws, size_t ws_size,
                              hipStream_t stream) {
  const float* x     = (const float*)d_in[0];
  const float* res   = (const float*)d_in[1];
  const float* gamma = (const float*)d_in[2];
  int* out = (int*)d_out;

  char* ws = (char*)d_ws;
  float* gmax   = (float*)ws;
  float* rowmax = (float*)(ws + 256);
  float* rstd   = (float*)(ws + 256 + 64 * 1024);
  const size_t yg_off = (size_t)1 << 20;
  const size_t need = yg_off + (size_t)NROWS * DD * 2;  // ~129 MB

  if (ws_size >= need) {
    __half* yg = (__half*)(ws + yg_off);
    pass1<<<NROWS, 256, 0, stream>>>(x, res, gamma, yg, rstd, rowmax);
    reduce_gmax<<<1, 1024, 0, stream>>>(rowmax, gmax);
    pass2<<<((size_t)NROWS * DD) / 2048, 256, 0, stream>>>(
        yg, rstd, gmax, out);
  } else {
    pass1_nb<<<NROWS, 256, 0, stream>>>(x, res, gamma, rstd, rowmax);
    reduce_gmax<<<1, 1024, 0, stream>>>(rowmax, gmax);
    pass2_nb<<<NROWS, 256, 0, stream>>>(x, res, gamma, rstd, gmax, out);
  }
}

// Round 10
// 204.535 us; speedup vs baseline: 1.9767x; 1.0103x over previous
//
#include <hip/hip_runtime.h>
#include <hip/hip_fp16.h>

#define DD 4096
#define NROWS 16384
#define EPS 1e-6f

typedef float  fx4 __attribute__((ext_vector_type(4)));
typedef int    ix4 __attribute__((ext_vector_type(4)));

// ws layout:
//   +0        : float gmax
//   +256      : float rowmax[16384]
//   +256+64K  : float rstd[16384]
//   +1MB      : fp16 yg[64M] = (x+res)*gamma, UNNORMALIZED (128 MB)

// Pass 1: block-per-row. ALL 12 loads batched into live registers (forces
// deep memory-level parallelism), all 4 packed fp16 stores issued at the
// end into DISTINCT registers (no store-data register reuse -> no
// vmcnt-on-store stall inside the loop). launch_bounds(256,2) lifts the
// VGPR cap so the batch stays in registers (prior variants: 28 VGPRs).
__global__ __launch_bounds__(256, 2) void pass1(
    const float* __restrict__ x, const float* __restrict__ res,
    const float* __restrict__ gamma, __half* __restrict__ yg,
    float* __restrict__ rstd, float* __restrict__ rowmax) {
  const int row = blockIdx.x;
  const int t = threadIdx.x;
  const fx4* x4 = (const fx4*)(x + (size_t)row * DD);
  const fx4* r4 = (const fx4*)(res + (size_t)row * DD);
  const fx4* g4 = (const fx4*)gamma;
  unsigned long long* yrow = (unsigned long long*)(yg + (size_t)row * DD);

  fx4 xv[4], rv[4], gv[4];
#pragma unroll
  for (int i = 0; i < 4; ++i) xv[i] = x4[t + i * 256];
#pragma unroll
  for (int i = 0; i < 4; ++i) rv[i] = r4[t + i * 256];
#pragma unroll
  for (int i = 0; i < 4; ++i) gv[i] = g4[t + i * 256];

  float ss = 0.f, mx = 0.f;
  unsigned long long pk[4];
#pragma unroll
  for (int i = 0; i < 4; ++i) {
    fx4 y = xv[i] + rv[i];
    ss += y.x * y.x + y.y * y.y + y.z * y.z + y.w * y.w;
    fx4 p = y * gv[i];
    mx = fmaxf(mx, fmaxf(fmaxf(fabsf(p.x), fabsf(p.y)),
                         fmaxf(fabsf(p.z), fabsf(p.w))));
    union { unsigned long long u; __half2 h2[2]; } c;
    c.h2[0] = __floats2half2_rn(p.x, p.y);
    c.h2[1] = __floats2half2_rn(p.z, p.w);
    pk[i] = c.u;
  }
#pragma unroll
  for (int i = 0; i < 4; ++i) yrow[t + i * 256] = pk[i];

#pragma unroll
  for (int off = 32; off > 0; off >>= 1) {
    ss += __shfl_down(ss, off, 64);
    mx = fmaxf(mx, __shfl_down(mx, off, 64));
  }
  __shared__ float s_ss[4], s_mx[4];
  const int wave = t >> 6, lane = t & 63;
  if (lane == 0) { s_ss[wave] = ss; s_mx[wave] = mx; }
  __syncthreads();
  if (t == 0) {
    float tss = s_ss[0] + s_ss[1] + s_ss[2] + s_ss[3];
    float tmx = fmaxf(fmaxf(s_mx[0], s_mx[1]), fmaxf(s_mx[2], s_mx[3]));
    float rs = rsqrtf(tss * (1.0f / DD) + EPS);
    rstd[row] = rs;
    rowmax[row] = tmx * rs;  // |normalized output| row max
  }
}

__global__ __launch_bounds__(1024) void reduce_gmax(
    const float* __restrict__ rowmax, float* __restrict__ gmax) {
  const int t = threadIdx.x;
  float m = 0.f;
#pragma unroll
  for (int i = 0; i < NROWS / 1024; ++i) m = fmaxf(m, rowmax[t + i * 1024]);
#pragma unroll
  for (int off = 32; off > 0; off >>= 1) m = fmaxf(m, __shfl_down(m, off, 64));
  __shared__ float s[16];
  if ((t & 63) == 0) s[t >> 6] = m;
  __syncthreads();
  if (t == 0) {
    float r = s[0];
#pragma unroll
    for (int i = 1; i < 16; ++i) r = fmaxf(r, s[i]);
    *gmax = r;
  }
}

// Pass 2: q = clamp(rn(fp16(y*gamma) * rstd[row] * 127/gmax)).
__global__ __launch_bounds__(256) void pass2(
    const __half* __restrict__ yg, const float* __restrict__ rstd,
    const float* __restrict__ gmax, int* __restrict__ out) {
  const int row = blockIdx.x >> 1;
  const float c = rstd[row] * (127.0f / *gmax);
  const size_t base = ((size_t)blockIdx.x * 256 + threadIdx.x) * 8;
  union { ix4 v; __half h[8]; } u;
  u.v = *(const ix4*)(yg + base);
  ix4 q0, q1;
  q0.x = min(max(__float2int_rn(__half2float(u.h[0]) * c), -128), 127);
  q0.y = min(max(__float2int_rn(__half2float(u.h[1]) * c), -128), 127);
  q0.z = min(max(__float2int_rn(__half2float(u.h[2]) * c), -128), 127);
  q0.w = min(max(__float2int_rn(__half2float(u.h[3]) * c), -128), 127);
  q1.x = min(max(__float2int_rn(__half2float(u.h[4]) * c), -128), 127);
  q1.y = min(max(__float2int_rn(__half2float(u.h[5]) * c), -128), 127);
  q1.z = min(max(__float2int_rn(__half2float(u.h[6]) * c), -128), 127);
  q1.w = min(max(__float2int_rn(__half2float(u.h[7]) * c), -128), 127);
  *(ix4*)(out + base) = q0;
  *(ix4*)(out + base + 4) = q1;
}

// ---- Fallback (ws too small): recompute path, atomic-free ----
__global__ __launch_bounds__(256) void pass1_nb(
    const float* __restrict__ x, const float* __restrict__ res,
    const float* __restrict__ gamma, float* __restrict__ rstd,
    float* __restrict__ rowmax) {
  const int row = blockIdx.x;
  const int t = threadIdx.x;
  const fx4* x4 = (const fx4*)(x + (size_t)row * DD);
  const fx4* r4 = (const fx4*)(res + (size_t)row * DD);
  const fx4* g4 = (const fx4*)gamma;
  float ss = 0.f, mx = 0.f;
#pragma unroll
  for (int i = 0; i < 4; ++i) {
    const int idx = t + i * 256;
    fx4 xv = x4[idx], rv = r4[idx], gv = g4[idx];
    float y0 = xv.x + rv.x, y1 = xv.y + rv.y;
    float y2 = xv.z + rv.z, y3 = xv.w + rv.w;
    ss += y0 * y0 + y1 * y1 + y2 * y2 + y3 * y3;
    mx = fmaxf(mx, fmaxf(fmaxf(fabsf(y0 * gv.x), fabsf(y1 * gv.y)),
                         fmaxf(fabsf(y2 * gv.z), fabsf(y3 * gv.w))));
  }
#pragma unroll
  for (int off = 32; off > 0; off >>= 1) {
    ss += __shfl_down(ss, off, 64);
    mx = fmaxf(mx, __shfl_down(mx, off, 64));
  }
  __shared__ float s_ss[4], s_mx[4];
  const int wave = t >> 6, lane = t & 63;
  if (lane == 0) { s_ss[wave] = ss; s_mx[wave] = mx; }
  __syncthreads();
  if (t == 0) {
    float tss = s_ss[0] + s_ss[1] + s_ss[2] + s_ss[3];
    float tmx = fmaxf(fmaxf(s_mx[0], s_mx[1]), fmaxf(s_mx[2], s_mx[3]));
    float rs = rsqrtf(tss * (1.0f / DD) + EPS);
    rstd[row] = rs;
    rowmax[row] = tmx * rs;
  }
}

__global__ __launch_bounds__(256) void pass2_nb(
    const float* __restrict__ x, const float* __restrict__ res,
    const float* __restrict__ gamma, const float* __restrict__ rstd,
    const float* __restrict__ gmax, int* __restrict__ out) {
  const int row = blockIdx.x;
  const int t = threadIdx.x;
  const float c = rstd[row] * (127.0f / *gmax);
  const fx4* x4 = (const fx4*)(x + (size_t)row * DD);
  const fx4* r4 = (const fx4*)(res + (size_t)row * DD);
  const fx4* g4 = (const fx4*)gamma;
  ix4* o4 = (ix4*)(out + (size_t)row * DD);
#pragma unroll
  for (int i = 0; i < 4; ++i) {
    const int idx = t + i * 256;
    fx4 xv = x4[idx], rv = r4[idx], gv = g4[idx];
    ix4 q;
    q.x = min(max(__float2int_rn((xv.x + rv.x) * gv.x * c), -128), 127);
    q.y = min(max(__float2int_rn((xv.y + rv.y) * gv.y * c), -128), 127);
    q.z = min(max(__float2int_rn((xv.z + rv.z) * gv.z * c), -128), 127);
    q.w = min(max(__float2int_rn((xv.w + rv.w) * gv.w * c), -128), 127);
    o4[idx] = q;
  }
}

extern "C" void kernel_launch(void* const* d_in, const int* in_sizes, int n_in,
                              void* d_out, int out_size, void* d_ws, size_t ws_size,
                              hipStream_t stream) {
  const float* x     = (const float*)d_in[0];
  const float* res   = (const float*)d_in[1];
  const float* gamma = (const float*)d_in[2];
  int* out = (int*)d_out;

  char* ws = (char*)d_ws;
  float* gmax   = (float*)ws;
  float* rowmax = (float*)(ws + 256);
  float* rstd   = (float*)(ws + 256 + 64 * 1024);
  const size_t yg_off = (size_t)1 << 20;
  const size_t need = yg_off + (size_t)NROWS * DD * 2;  // ~129 MB

  if (ws_size >= need) {
    __half* yg = (__half*)(ws + yg_off);
    pass1<<<NROWS, 256, 0, stream>>>(x, res, gamma, yg, rstd, rowmax);
    reduce_gmax<<<1, 1024, 0, stream>>>(rowmax, gmax);
    pass2<<<((size_t)NROWS * DD) / 2048, 256, 0, stream>>>(
        yg, rstd, gmax, out);
  } else {
    pass1_nb<<<NROWS, 256, 0, stream>>>(x, res, gamma, rstd, rowmax);
    reduce_gmax<<<1, 1024, 0, stream>>>(rowmax, gmax);
    pass2_nb<<<NROWS, 256, 0, stream>>>(x, res, gamma, rstd, gmax, out);
  }
}